// Round 4
// baseline (903.106 us; speedup 1.0000x reference)
//
#include <hip/hip_runtime.h>
#include <cstdint>
#include <cstddef>

#define EPSF 1e-6f

static constexpr int Bc  = 4;
static constexpr int Nc  = 4096;
static constexpr int Cch = 1024;
static constexpr int Hc  = 16;
static constexpr int Dc  = 64;
static constexpr int BHc = Bc * Hc;                      // 64
static constexpr size_t HEADSZ = (size_t)BHc * Nc * Dc;  // 16,777,216 floats
static constexpr int Kd  = 1024;                         // inner dim of both GEMMs

typedef __attribute__((ext_vector_type(8))) short     s16x8;
typedef __attribute__((ext_vector_type(4))) float     f32x4;

__device__ __forceinline__ float sigmoid_f(float x) {
  return 1.0f / (1.0f + __expf(-x));
}

// ---- bf16 helpers ---------------------------------------------------------
__device__ __forceinline__ unsigned short bf16_rne(float x) {
  unsigned int b = __float_as_uint(x);
  b += 0x7fffu + ((b >> 16) & 1u);
  return (unsigned short)(b >> 16);
}
__device__ __forceinline__ float bf16_to_f(unsigned short u) {
  return __uint_as_float(((unsigned int)u) << 16);
}
// truncating split: x = hi + lo + O(2^-16 |x|); hi/lo both bf16
__device__ __forceinline__ void split_trunc(float x, unsigned short& h, unsigned short& l) {
  unsigned int b  = __float_as_uint(x);
  unsigned int hb = b & 0xffff0000u;
  h = (unsigned short)(hb >> 16);
  float res = x - __uint_as_float(hb);
  l = (unsigned short)(__float_as_uint(res) >> 16);
}

// async global->LDS, 16B per lane; LDS dest = wave-uniform base + lane*16
__device__ __forceinline__ void gl_lds16(const unsigned short* g, unsigned short* l) {
  __builtin_amdgcn_global_load_lds(
      (const __attribute__((address_space(1))) unsigned int*)(const void*)g,
      (__attribute__((address_space(3))) unsigned int*)(void*)l,
      16, 0, 0);
}

// ---------------------------------------------------------------------------
// One-time weight split: fp32 -> (hi, lo) bf16, RNE both.  n4 = nelems/4.
// ---------------------------------------------------------------------------
__global__ __launch_bounds__(256)
void split_kernel(const float* __restrict__ in, unsigned short* __restrict__ hi,
                  unsigned short* __restrict__ lo, int n4)
{
  int i = blockIdx.x * 256 + threadIdx.x;
  if (i >= n4) return;
  float4 v = ((const float4*)in)[i];
  ushort4 h, l;
  h.x = bf16_rne(v.x); l.x = bf16_rne(v.x - bf16_to_f(h.x));
  h.y = bf16_rne(v.y); l.y = bf16_rne(v.y - bf16_to_f(h.y));
  h.z = bf16_rne(v.z); l.z = bf16_rne(v.z - bf16_to_f(h.z));
  h.w = bf16_rne(v.w); l.w = bf16_rne(v.w - bf16_to_f(h.w));
  ((ushort4*)hi)[i] = h;
  ((ushort4*)lo)[i] = l;
}

// ---------------------------------------------------------------------------
// bf16x3 MFMA GEMM (TN): out[m][r] = sum_c A[m][c]*W[r][c] + bias[r]
// MODE 0: A = fp32 x (split in-kernel, reg path). N=3072. Scatter q/k/v with
//         sigmoid on q,k; fused q_sum/k_sum (post-sigmoid column sums).
// MODE 1: A = pre-split bf16 hi/lo (attn), staged via global_load_lds. N=1024.
// W hi/lo staged via global_load_lds (both modes), [128][32] ushort tiles are
// thread-linear so the wave-uniform-base + lane*16 DMA layout matches exactly.
// Block: 256 thr = 4 waves (2x2), tile 128x128x32, wave tile 64x64 = 4x4 frags
// of v_mfma_f32_16x16x32_bf16; 3 MFMAs per frag pair (hh + hl + lh).
// XCD-bijective block swizzle (grid sizes divisible by 8).
// ---------------------------------------------------------------------------
template <int MODE>
__global__ __launch_bounds__(256)
void gemm_mfma(const void* __restrict__ A_any, const unsigned short* __restrict__ Al_g,
               const unsigned short* __restrict__ Wh_g, const unsigned short* __restrict__ Wl_g,
               const float* __restrict__ bias,
               float* __restrict__ out0, float* __restrict__ out1, float* __restrict__ out2,
               float* __restrict__ qsum_g, float* __restrict__ ksum_g)
{
  __shared__ unsigned short Ahs[128][32];
  __shared__ unsigned short Als[128][32];
  __shared__ unsigned short Whs[128][32];
  __shared__ unsigned short Wls[128][32];

  // XCD-aware bijective swizzle: nwg % 8 == 0 for both grids.
  const int gx  = gridDim.x;
  const int nwg = gx * gridDim.y;
  const int bid = blockIdx.y * gx + blockIdx.x;
  const int swz = (bid & 7) * (nwg >> 3) + (bid >> 3);
  const int bx  = swz % gx;
  const int by  = swz / gx;

  const int t    = threadIdx.x;
  const int lane = t & 63;
  const int wid  = t >> 6;
  const int wr   = wid >> 1, wc = wid & 1;
  const int r16  = lane & 15, g = lane >> 4;
  const int m0   = bx * 128;
  const int r0   = by * 128;

  // DMA staging geometry: wave wid covers rows [wid*32, wid*32+32), two 16-row
  // segments j=0,1; lane l -> row +(l>>2), ushort col (l&3)*8.
  const int wrow = wid * 32;
  const int wl_r = lane >> 2;
  const int wl_c = (lane & 3) * 8;
  unsigned short* AhsF = &Ahs[0][0];
  unsigned short* AlsF = &Als[0][0];
  unsigned short* WhsF = &Whs[0][0];
  unsigned short* WlsF = &Wls[0][0];

  f32x4 acc[4][4];
#pragma unroll
  for (int i = 0; i < 4; ++i)
#pragma unroll
    for (int j = 0; j < 4; ++j) acc[i][j] = (f32x4){0.f, 0.f, 0.f, 0.f};

  const float* Af = (const float*)A_any;
  const unsigned short* Ah_g = (const unsigned short*)A_any;

  // MODE 0 fp32-A register staging: rows arow0+32j, 16B col chunk ac4
  const int arow0 = t >> 3, ac4 = t & 7;
  float4 fa[4];
  if constexpr (MODE == 0) {
#pragma unroll
    for (int j = 0; j < 4; ++j)
      fa[j] = *(const float4*)&Af[(size_t)(m0 + arow0 + 32*j) * Kd + ac4 * 4];
  }

  for (int kt = 0; kt < Kd; kt += 32) {
    __syncthreads();   // previous tile fully consumed
    // ---- stage A ----
    if constexpr (MODE == 0) {
#pragma unroll
      for (int j = 0; j < 4; ++j) {
        const int row = arow0 + 32*j;
        ushort4 h, l;
        split_trunc(fa[j].x, h.x, l.x);
        split_trunc(fa[j].y, h.y, l.y);
        split_trunc(fa[j].z, h.z, l.z);
        split_trunc(fa[j].w, h.w, l.w);
        *(ushort4*)&Ahs[row][ac4 * 4] = h;
        *(ushort4*)&Als[row][ac4 * 4] = l;
      }
    } else {
#pragma unroll
      for (int j = 0; j < 2; ++j) {
        const size_t gof = (size_t)(m0 + wrow + j*16 + wl_r) * Kd + kt + wl_c;
        const int    lof = wid * 1024 + j * 512;
        gl_lds16(Ah_g + gof, AhsF + lof);
        gl_lds16(Al_g + gof, AlsF + lof);
      }
    }
    // ---- stage W (DMA) ----
#pragma unroll
    for (int j = 0; j < 2; ++j) {
      const size_t gof = (size_t)(r0 + wrow + j*16 + wl_r) * Kd + kt + wl_c;
      const int    lof = wid * 1024 + j * 512;
      gl_lds16(Wh_g + gof, WhsF + lof);
      gl_lds16(Wl_g + gof, WlsF + lof);
    }
    __syncthreads();   // staging complete (compiler drains vmcnt+lgkmcnt)

    // ---- prefetch next A fp32 tile (in flight during MFMA phase) ----
    if constexpr (MODE == 0) {
      if (kt + 32 < Kd) {
        const int kn = kt + 32;
#pragma unroll
        for (int j = 0; j < 4; ++j)
          fa[j] = *(const float4*)&Af[(size_t)(m0 + arow0 + 32*j) * Kd + kn + ac4 * 4];
      }
    }

    // ---- fragments + MFMA ----
    s16x8 fah[4], fal[4], fbh[4], fbl[4];
#pragma unroll
    for (int i = 0; i < 4; ++i) {
      const int row = wr * 64 + i * 16 + r16;
      fah[i] = *(const s16x8*)&Ahs[row][g * 8];
      fal[i] = *(const s16x8*)&Als[row][g * 8];
    }
#pragma unroll
    for (int j = 0; j < 4; ++j) {
      const int row = wc * 64 + j * 16 + r16;
      fbh[j] = *(const s16x8*)&Whs[row][g * 8];
      fbl[j] = *(const s16x8*)&Wls[row][g * 8];
    }
#pragma unroll
    for (int i = 0; i < 4; ++i) {
#pragma unroll
      for (int j = 0; j < 4; ++j) {
        acc[i][j] = __builtin_amdgcn_mfma_f32_16x16x32_bf16(fah[i], fbh[j], acc[i][j], 0, 0, 0);
        acc[i][j] = __builtin_amdgcn_mfma_f32_16x16x32_bf16(fah[i], fbl[j], acc[i][j], 0, 0, 0);
        acc[i][j] = __builtin_amdgcn_mfma_f32_16x16x32_bf16(fal[i], fbh[j], acc[i][j], 0, 0, 0);
      }
    }
  }

  // ---- epilogue (C/D frag: col = lane&15, row = (lane>>4)*4 + reg) ----
#pragma unroll
  for (int nj = 0; nj < 4; ++nj) {
    const int colb = r0 + wc * 64 + nj * 16;   // 16-aligned -> frag within one (tsel,h) block
    const float bj = bias[colb + r16];
    if constexpr (MODE == 0) {
      const int tsel = colb >> 10;
      const int h    = (colb & 1023) >> 6;
      const int d    = (colb & 63) + r16;
      float* dst = (tsel == 0) ? out0 : (tsel == 1) ? out1 : out2;
      const bool sig = (tsel < 2);
      float ssum = 0.f;
#pragma unroll
      for (int mi = 0; mi < 4; ++mi) {
#pragma unroll
        for (int rg = 0; rg < 4; ++rg) {
          const int m = m0 + wr * 64 + mi * 16 + g * 4 + rg;
          float xv = acc[mi][nj][rg] + bj;
          if (sig) { xv = sigmoid_f(xv); ssum += xv; }
          const int b = m >> 12, n = m & 4095;
          dst[((size_t)(b * Hc + h) * Nc + n) * Dc + d] = xv;
        }
      }
      if (sig) {
        // fused q_sum/k_sum: reduce over the 4 row-groups (lane bits 4,5)
        ssum += __shfl_xor(ssum, 16);
        ssum += __shfl_xor(ssum, 32);
        if (g == 0) {
          const int b = (m0 + wr * 64) >> 12;   // uniform within wave slice
          float* sdst = (tsel == 0) ? qsum_g : ksum_g;
          atomicAdd(&sdst[(b * Hc + h) * 64 + d], ssum);
        }
      }
    } else {
#pragma unroll
      for (int mi = 0; mi < 4; ++mi) {
#pragma unroll
        for (int rg = 0; rg < 4; ++rg) {
          const int m = m0 + wr * 64 + mi * 16 + g * 4 + rg;
          out0[(size_t)m * 1024 + colb + r16] = acc[mi][nj][rg] + bj;
        }
      }
    }
  }
}

// ---------------------------------------------------------------------------
// K3: si[n]=1/sum_d (q+e)(k_sum+e); so[n]=1/sum_d (k+e)(q_sum+e)
//     q_si_sum[d] += q[n,d]*si[n];  k_so_sum[d] += k[n,d]*so[n]
// ---------------------------------------------------------------------------
__global__ __launch_bounds__(256)
void siso_kernel(const float* __restrict__ qb, const float* __restrict__ kb,
                 const float* __restrict__ q_sum, const float* __restrict__ k_sum,
                 float* __restrict__ si, float* __restrict__ so,
                 float* __restrict__ q_si_sum, float* __restrict__ k_so_sum)
{
  const int bh = blockIdx.x, chunk = blockIdx.y;
  const int t = threadIdx.x, lane = t & 63, w = t >> 6;
  const float ksd = k_sum[bh*64 + lane] + EPSF;
  const float qsd = q_sum[bh*64 + lane] + EPSF;
  float kso_p = 0.f, qsi_p = 0.f;
  const size_t rowbase = (size_t)bh * Nc;
  for (int i = 0; i < 128; ++i) {
    const int n = chunk*512 + i*4 + w;
    const size_t off = (rowbase + n) * Dc + lane;
    const float qv = qb[off];
    const float kv = kb[off];
    float s1 = (qv + EPSF) * ksd;
    float s2 = (kv + EPSF) * qsd;
#pragma unroll
    for (int o = 32; o > 0; o >>= 1) {
      s1 += __shfl_xor(s1, o);
      s2 += __shfl_xor(s2, o);
    }
    const float si_n = 1.f / s1;
    const float so_n = 1.f / s2;
    if (lane == 0) { si[rowbase + n] = si_n; so[rowbase + n] = so_n; }
    qsi_p = __builtin_fmaf(qv, si_n, qsi_p);
    kso_p = __builtin_fmaf(kv, so_n, kso_p);
  }
  __shared__ float red[2][4][64];
  red[0][w][lane] = qsi_p; red[1][w][lane] = kso_p;
  __syncthreads();
  if (t < 64) {
    atomicAdd(&q_si_sum[bh*64 + t], red[0][0][t]+red[0][1][t]+red[0][2][t]+red[0][3][t]);
  } else if (t < 128) {
    const int l = t - 64;
    atomicAdd(&k_so_sum[bh*64 + l], red[1][0][l]+red[1][1][l]+red[1][2][l]+red[1][3][l]);
  }
}

// ---------------------------------------------------------------------------
// K4: conserved sink/source -> qscale (sa*si), sc_raw (exp), exp_sum
// ---------------------------------------------------------------------------
__global__ __launch_bounds__(256)
void conserved_kernel(const float* __restrict__ qb, const float* __restrict__ kb,
                      const float* __restrict__ q_si_sum, const float* __restrict__ k_so_sum,
                      const float* __restrict__ si,
                      float* __restrict__ qscale, float* __restrict__ sc_raw,
                      float* __restrict__ exp_sum)
{
  const int bh = blockIdx.x, chunk = blockIdx.y;
  const int t = threadIdx.x, lane = t & 63, w = t >> 6;
  const float ksod = k_so_sum[bh*64 + lane] + EPSF;
  const float qsid = q_si_sum[bh*64 + lane] + EPSF;
  float ep = 0.f;
  const size_t rowbase = (size_t)bh * Nc;
  for (int i = 0; i < 128; ++i) {
    const int n = chunk*512 + i*4 + w;
    const size_t off = (rowbase + n) * Dc + lane;
    const float qv = qb[off];
    const float kv = kb[off];
    float s1 = (qv + EPSF) * ksod;
    float s2 = (kv + EPSF) * qsid;
#pragma unroll
    for (int o = 32; o > 0; o >>= 1) {
      s1 += __shfl_xor(s1, o);
      s2 += __shfl_xor(s2, o);
    }
    const float sa = sigmoid_f(s1 + EPSF);
    float cs = s2 + EPSF;
    cs = fminf(fmaxf(cs, -1.f), 1.f);
    const float e = __expf(cs);
    if (lane == 0) {
      qscale[rowbase + n] = sa * si[rowbase + n];
      sc_raw[rowbase + n] = e;
      ep += e;
    }
  }
  __shared__ float red[4];
  if (lane == 0) red[w] = ep;
  __syncthreads();
  if (t == 0) atomicAdd(&exp_sum[bh], red[0]+red[1]+red[2]+red[3]);
}

// ---------------------------------------------------------------------------
// K6: kv[bh][d][m] = sum_n k[n,d] * v[n,m] * sc[n],  sc = sc_raw*N/exp_sum
// ---------------------------------------------------------------------------
__global__ __launch_bounds__(256)
void kv_kernel(const float* __restrict__ kb, const float* __restrict__ vb,
               const float* __restrict__ sc_raw, const float* __restrict__ exp_sum,
               float* __restrict__ kvout)
{
  const int bh = blockIdx.x, ch = blockIdx.y;
  const int t = threadIdx.x;
  const int m = t & 63, dg = t >> 6;
  const float scl = (float)Nc / exp_sum[bh];
  __shared__ float ks[64][64];
  __shared__ float vs[64][64];
  float acc[16];
#pragma unroll
  for (int i = 0; i < 16; ++i) acc[i] = 0.f;

  for (int c0 = ch*1024; c0 < (ch+1)*1024; c0 += 64) {
    __syncthreads();
#pragma unroll
    for (int j = 0; j < 4; ++j) {
      const int f = t + 256*j;
      const int row = f >> 4, cb = (f & 15) * 4;
      const size_t gidx = ((size_t)bh*Nc + c0 + row) * Dc + cb;
      *(float4*)&ks[row][cb] = *(const float4*)&kb[gidx];
      float4 vv = *(const float4*)&vb[gidx];
      const float s = sc_raw[(size_t)bh*Nc + c0 + row] * scl;
      vv.x *= s; vv.y *= s; vv.z *= s; vv.w *= s;
      *(float4*)&vs[row][cb] = vv;
    }
    __syncthreads();
#pragma unroll 8
    for (int n = 0; n < 64; ++n) {
      const float vv = vs[n][m];
#pragma unroll
      for (int dd = 0; dd < 4; ++dd) {
        float4 kk = *(const float4*)&ks[n][dg*16 + dd*4];
        acc[dd*4+0] = __builtin_fmaf(kk.x, vv, acc[dd*4+0]);
        acc[dd*4+1] = __builtin_fmaf(kk.y, vv, acc[dd*4+1]);
        acc[dd*4+2] = __builtin_fmaf(kk.z, vv, acc[dd*4+2]);
        acc[dd*4+3] = __builtin_fmaf(kk.w, vv, acc[dd*4+3]);
      }
    }
  }
#pragma unroll
  for (int dd = 0; dd < 16; ++dd)
    atomicAdd(&kvout[(size_t)bh*4096 + (size_t)(dg*16 + dd)*64 + m], acc[dd]);
}

// ---------------------------------------------------------------------------
// K7: attn[m][h*64+mm] = qscale[n] * sum_d q[n,d]*kv[d][mm] -> bf16 hi/lo
// ---------------------------------------------------------------------------
__global__ __launch_bounds__(256)
void out_kernel(const float* __restrict__ qb, const float* __restrict__ kvin,
                const float* __restrict__ qscale,
                unsigned short* __restrict__ attn_h, unsigned short* __restrict__ attn_l)
{
  const int bh = blockIdx.x, cy = blockIdx.y;
  const int t = threadIdx.x;
  const int c0 = cy * 64;
  __shared__ float kvs[64][68];
  __shared__ float qT[64][68];
  __shared__ float qsc[64];

#pragma unroll
  for (int j = 0; j < 4; ++j) {
    const int f = t + 256*j;
    const int d = f >> 4, cb = (f & 15) * 4;
    *(float4*)&kvs[d][cb] = *(const float4*)&kvin[(size_t)bh*4096 + (size_t)d*64 + cb];
  }
#pragma unroll
  for (int j = 0; j < 4; ++j) {
    const int f = t + 256*j;
    const int n = f >> 4, db = (f & 15) * 4;
    float4 qv = *(const float4*)&qb[((size_t)bh*Nc + c0 + n) * Dc + db];
    qT[db+0][n] = qv.x; qT[db+1][n] = qv.y; qT[db+2][n] = qv.z; qT[db+3][n] = qv.w;
  }
  if (t < 16) *(float4*)&qsc[t*4] = *(const float4*)&qscale[(size_t)bh*Nc + c0 + t*4];
  __syncthreads();

  const int ng = t & 15, mg = t >> 4;
  float acc[4][4];
#pragma unroll
  for (int i = 0; i < 4; ++i)
#pragma unroll
    for (int j = 0; j < 4; ++j) acc[i][j] = 0.f;

#pragma unroll 16
  for (int d = 0; d < 64; ++d) {
    float4 a = *(const float4*)&qT[d][ng*4];
    float4 b = *(const float4*)&kvs[d][mg*4];
    float av[4] = {a.x,a.y,a.z,a.w};
    float bv[4] = {b.x,b.y,b.z,b.w};
#pragma unroll
    for (int i = 0; i < 4; ++i)
#pragma unroll
      for (int j = 0; j < 4; ++j)
        acc[i][j] = __builtin_fmaf(av[i], bv[j], acc[i][j]);
  }

  const int b = bh >> 4, h = bh & 15;
#pragma unroll
  for (int i = 0; i < 4; ++i) {
    const int n = c0 + ng*4 + i;
    const float s = qsc[ng*4 + i];
    const size_t base = ((size_t)b * Nc + n) * 1024 + h * Dc + mg * 4;
    ushort4 hh, ll;
    float v0 = acc[i][0]*s, v1 = acc[i][1]*s, v2 = acc[i][2]*s, v3 = acc[i][3]*s;
    split_trunc(v0, hh.x, ll.x);
    split_trunc(v1, hh.y, ll.y);
    split_trunc(v2, hh.z, ll.z);
    split_trunc(v3, hh.w, ll.w);
    *(ushort4*)&attn_h[base] = hh;
    *(ushort4*)&attn_l[base] = ll;
  }
}

// ---------------------------------------------------------------------------
extern "C" void kernel_launch(void* const* d_in, const int* in_sizes, int n_in,
                              void* d_out, int out_size, void* d_ws, size_t ws_size,
                              hipStream_t stream)
{
  const float* x      = (const float*)d_in[0];
  const float* qkv_w  = (const float*)d_in[1];
  const float* qkv_b  = (const float*)d_in[2];
  const float* proj_w = (const float*)d_in[3];
  const float* proj_b = (const float*)d_in[4];
  float* out = (float*)d_out;
  float* ws  = (float*)d_ws;

  float* qb = ws;
  float* kb = ws + HEADSZ;
  float* vb = ws + 2*HEADSZ;
  // attn (bf16 hi/lo) aliases vb: v is dead after kv_kernel.
  unsigned short* attn_h = (unsigned short*)vb;
  unsigned short* attn_l = attn_h + HEADSZ;     // HEADSZ ushorts

  float* sm      = ws + 3*HEADSZ;
  float* q_sum   = sm;                  // 4096
  float* k_sum   = sm + 4096;           // 4096
  float* q_si    = sm + 8192;           // 4096
  float* k_so    = sm + 12288;          // 4096
  float* exp_sum = sm + 16384;          // 64 (padded to 4096)
  float* si      = sm + 20480;          // 262144
  float* so      = si + 262144;
  float* qscale  = so + 262144;
  float* sc_raw  = qscale + 262144;
  float* kvbuf   = sc_raw + 262144;     // 262144

  unsigned short* Wh = (unsigned short*)(kvbuf + 262144);  // 3072*1024
  unsigned short* Wl = Wh + 3145728;
  unsigned short* Ph = Wl + 3145728;                       // 1024*1024
  unsigned short* Pl = Ph + 1048576;

  hipMemsetAsync(sm, 0, 20480 * sizeof(float), stream);
  hipMemsetAsync(kvbuf, 0, 262144 * sizeof(float), stream);

  // one-time weight splits (memory-bound, ~10 us)
  split_kernel<<<3072, 256, 0, stream>>>(qkv_w, Wh, Wl, 786432);
  split_kernel<<<1024, 256, 0, stream>>>(proj_w, Ph, Pl, 262144);

  // QKV: (16384x1024) x (3072x1024)^T -> q,k,v (sigmoid on q,k; fused sums)
  gemm_mfma<0><<<dim3(128, 24), 256, 0, stream>>>(x, nullptr, Wh, Wl, qkv_b,
                                                  qb, kb, vb, q_sum, k_sum);

  siso_kernel<<<dim3(64, 8), 256, 0, stream>>>(qb, kb, q_sum, k_sum, si, so, q_si, k_so);
  conserved_kernel<<<dim3(64, 8), 256, 0, stream>>>(qb, kb, q_si, k_so, si, qscale, sc_raw, exp_sum);
  kv_kernel<<<dim3(64, 4), 256, 0, stream>>>(kb, vb, sc_raw, exp_sum, kvbuf);
  out_kernel<<<dim3(64, 64), 256, 0, stream>>>(qb, kvbuf, qscale, attn_h, attn_l);

  // proj: (16384x1024 bf16 hi/lo) x (1024x1024)^T -> out
  gemm_mfma<1><<<dim3(128, 8), 256, 0, stream>>>(attn_h, attn_l, Ph, Pl, proj_b,
                                                 out, nullptr, nullptr, nullptr, nullptr);
}